// Round 1
// baseline (300.946 us; speedup 1.0000x reference)
//
#include <hip/hip_runtime.h>
#include <cstdint>
#include <cstddef>

#define DI __device__ __forceinline__

typedef unsigned short u16;
typedef short bf16x8 __attribute__((ext_vector_type(8)));
typedef unsigned short u16x8 __attribute__((ext_vector_type(8)));
typedef float f32x4 __attribute__((ext_vector_type(4)));

static constexpr int DMODEL = 1024, T = 2048, BB = 4, NH = 16, HD = 64;
static constexpr int M = BB * T; // 8192

// workspace offsets in u16 elements
static constexpr size_t XB_OFF = 0;                                  // x bf16 [8192][1024]
static constexpr size_t WT_OFF = (size_t)M * DMODEL;                 // 4 x WtT bf16 [1024][1024]
static constexpr size_t Q_OFF  = WT_OFF + 4ull * DMODEL * DMODEL;    // Q [B,H,T,64]
static constexpr size_t K_OFF  = Q_OFF + (size_t)M * DMODEL;
static constexpr size_t V_OFF  = K_OFF + (size_t)M * DMODEL;
static constexpr size_t O_OFF  = XB_OFF;                             // attn out aliases xb

DI u16 f2bf(float x) {
  unsigned int u = __builtin_bit_cast(unsigned int, x);
  u += 0x7fffu + ((u >> 16) & 1u);
  return (u16)(u >> 16);
}

DI void gld_lds16(const void* g, void* l) {
  __builtin_amdgcn_global_load_lds(
      (const __attribute__((address_space(1))) void*)g,
      (__attribute__((address_space(3))) void*)l, 16, 0, 0);
}

// ---------------- cast x fp32 -> bf16 ----------------
__global__ void k_cast(const float* __restrict__ in, u16* __restrict__ out) {
  size_t i = (size_t)(blockIdx.x * 256 + threadIdx.x) * 8;
  float4 a = *(const float4*)(in + i);
  float4 b = *(const float4*)(in + i + 4);
  u16x8 v;
  v[0] = f2bf(a.x); v[1] = f2bf(a.y); v[2] = f2bf(a.z); v[3] = f2bf(a.w);
  v[4] = f2bf(b.x); v[5] = f2bf(b.y); v[6] = f2bf(b.z); v[7] = f2bf(b.w);
  *(u16x8*)(out + i) = v;
}

// ---------------- transpose+cast weights: W[K][N] f32 -> Wt[N][K] bf16 ----------------
__global__ void k_transw(const float* __restrict__ Wq, const float* __restrict__ Wk,
                         const float* __restrict__ Wv, const float* __restrict__ Wo,
                         u16* __restrict__ WtBase) {
  __shared__ u16 tile[32][33];
  const int z = blockIdx.z;
  const float* W = z == 0 ? Wq : (z == 1 ? Wk : (z == 2 ? Wv : Wo));
  u16* Wt = WtBase + (size_t)z * DMODEL * DMODEL;
  int tx = threadIdx.x, ty = threadIdx.y;
  int c = blockIdx.x * 32 + tx;
#pragma unroll
  for (int i = 0; i < 4; ++i) {
    int r = blockIdx.y * 32 + ty + i * 8;
    tile[ty + i * 8][tx] = f2bf(W[(size_t)r * DMODEL + c]);
  }
  __syncthreads();
#pragma unroll
  for (int i = 0; i < 4; ++i) {
    int rw = blockIdx.x * 32 + ty + i * 8;
    Wt[(size_t)rw * DMODEL + blockIdx.y * 32 + tx] = tile[tx][ty + i * 8];
  }
}

// ---------------- QKV projection GEMM: C = x @ W + b (bf16 MFMA, 128x128 tile, BK=64) ----
__launch_bounds__(256, 2)
__global__ void k_gemm_qkv(const u16* __restrict__ A, const u16* __restrict__ Wt,
                           const float* __restrict__ bq, const float* __restrict__ bk,
                           const float* __restrict__ bv,
                           u16* __restrict__ Qo, u16* __restrict__ Ko, u16* __restrict__ Vo) {
  __shared__ u16 As[128 * 64];
  __shared__ u16 Bs[128 * 64];
  const int z = blockIdx.z;
  const u16* Bt = Wt + (size_t)z * DMODEL * DMODEL;
  const float* bias = z == 0 ? bq : (z == 1 ? bk : bv);
  u16* out = z == 0 ? Qo : (z == 1 ? Ko : Vo);
  const float scale = z == 0 ? 0.125f : 1.0f;

  const int tid = threadIdx.x;
  const int wave = tid >> 6, lane = tid & 63;
  const int g = lane >> 4, l15 = lane & 15;
  const int brow = blockIdx.x * 128, bcol = blockIdx.y * 128;
  const int wr = wave >> 1, wc = wave & 1;
  const int srow = tid >> 3, schunk = tid & 7;

  f32x4 acc[4][4] = {};

  for (int k0 = 0; k0 < DMODEL; k0 += 64) {
    __syncthreads();
#pragma unroll
    for (int j = 0; j < 4; ++j) {
      int r = j * 32 + srow;
      int cs = (schunk ^ (r & 7)) * 8;
      gld_lds16(A + (size_t)(brow + r) * DMODEL + k0 + cs, (char*)As + j * 4096 + wave * 1024);
      gld_lds16(Bt + (size_t)(bcol + r) * DMODEL + k0 + cs, (char*)Bs + j * 4096 + wave * 1024);
    }
    __syncthreads();
#pragma unroll
    for (int kh = 0; kh < 2; ++kh) {
      bf16x8 af[4], bfr[4];
#pragma unroll
      for (int m = 0; m < 4; ++m) {
        int r = wr * 64 + m * 16 + l15;
        int ch = (kh * 4 + g) ^ (r & 7);
        af[m] = *(const bf16x8*)((const char*)As + r * 128 + ch * 16);
      }
#pragma unroll
      for (int n = 0; n < 4; ++n) {
        int r = wc * 64 + n * 16 + l15;
        int ch = (kh * 4 + g) ^ (r & 7);
        bfr[n] = *(const bf16x8*)((const char*)Bs + r * 128 + ch * 16);
      }
#pragma unroll
      for (int m = 0; m < 4; ++m)
#pragma unroll
        for (int n = 0; n < 4; ++n)
          acc[m][n] = __builtin_amdgcn_mfma_f32_16x16x32_bf16(af[m], bfr[n], acc[m][n], 0, 0, 0);
    }
  }

#pragma unroll
  for (int m = 0; m < 4; ++m)
#pragma unroll
    for (int n = 0; n < 4; ++n) {
      int col = bcol + wc * 64 + n * 16 + l15;
      float bias_v = bias[col];
      int h = col >> 6, d = col & 63;
#pragma unroll
      for (int r = 0; r < 4; ++r) {
        int row = brow + wr * 64 + m * 16 + g * 4 + r;
        int b = row >> 11, t = row & 2047;
        float v = (acc[m][n][r] + bias_v) * scale;
        out[(((size_t)(b * NH + h) * T + t) << 6) + d] = f2bf(v);
      }
    }
}

// ---------------- output projection GEMM: out = O @ Wo + bo (fp32 out) ----------------
__launch_bounds__(256, 2)
__global__ void k_gemm_out(const u16* __restrict__ A, const u16* __restrict__ Bt,
                           const float* __restrict__ bias, float* __restrict__ out) {
  __shared__ u16 As[128 * 64];
  __shared__ u16 Bs[128 * 64];
  const int tid = threadIdx.x;
  const int wave = tid >> 6, lane = tid & 63;
  const int g = lane >> 4, l15 = lane & 15;
  const int brow = blockIdx.x * 128, bcol = blockIdx.y * 128;
  const int wr = wave >> 1, wc = wave & 1;
  const int srow = tid >> 3, schunk = tid & 7;

  f32x4 acc[4][4] = {};

  for (int k0 = 0; k0 < DMODEL; k0 += 64) {
    __syncthreads();
#pragma unroll
    for (int j = 0; j < 4; ++j) {
      int r = j * 32 + srow;
      int cs = (schunk ^ (r & 7)) * 8;
      gld_lds16(A + (size_t)(brow + r) * DMODEL + k0 + cs, (char*)As + j * 4096 + wave * 1024);
      gld_lds16(Bt + (size_t)(bcol + r) * DMODEL + k0 + cs, (char*)Bs + j * 4096 + wave * 1024);
    }
    __syncthreads();
#pragma unroll
    for (int kh = 0; kh < 2; ++kh) {
      bf16x8 af[4], bfr[4];
#pragma unroll
      for (int m = 0; m < 4; ++m) {
        int r = wr * 64 + m * 16 + l15;
        int ch = (kh * 4 + g) ^ (r & 7);
        af[m] = *(const bf16x8*)((const char*)As + r * 128 + ch * 16);
      }
#pragma unroll
      for (int n = 0; n < 4; ++n) {
        int r = wc * 64 + n * 16 + l15;
        int ch = (kh * 4 + g) ^ (r & 7);
        bfr[n] = *(const bf16x8*)((const char*)Bs + r * 128 + ch * 16);
      }
#pragma unroll
      for (int m = 0; m < 4; ++m)
#pragma unroll
        for (int n = 0; n < 4; ++n)
          acc[m][n] = __builtin_amdgcn_mfma_f32_16x16x32_bf16(af[m], bfr[n], acc[m][n], 0, 0, 0);
    }
  }

#pragma unroll
  for (int m = 0; m < 4; ++m)
#pragma unroll
    for (int n = 0; n < 4; ++n) {
      int col = bcol + wc * 64 + n * 16 + l15;
      float bias_v = bias[col];
#pragma unroll
      for (int r = 0; r < 4; ++r) {
        int row = brow + wr * 64 + m * 16 + g * 4 + r;
        out[(size_t)row * DMODEL + col] = acc[m][n][r] + bias_v;
      }
    }
}

// ---------------- causal flash attention ----------------
// grid (16, 64): x = q-tile (reversed for load balance), y = b*16+h
// block 256 = 4 waves x 32 q-rows; KV tiles of 64
__launch_bounds__(256, 2)
__global__ void k_attn(const u16* __restrict__ Qw, const u16* __restrict__ Kw,
                       const u16* __restrict__ Vw, u16* __restrict__ Ow) {
  __shared__ u16 Ksh[64 * 64];
  __shared__ u16 Vt[64 * 64];
  __shared__ u16 Plds[4][32 * 64];

  const int tid = threadIdx.x;
  const int wave = tid >> 6, lane = tid & 63;
  const int g = lane >> 4, l15 = lane & 15;
  const int qt = 15 - blockIdx.x;
  const int bh = blockIdx.y;
  const u16* Qb = Qw + (size_t)bh * T * HD;
  const u16* Kb = Kw + (size_t)bh * T * HD;
  const u16* Vb = Vw + (size_t)bh * T * HD;

  // Q fragments in registers (Q already scaled by 1/8)
  bf16x8 qf[2][2];
#pragma unroll
  for (int m = 0; m < 2; ++m) {
    int qrow = qt * 128 + wave * 32 + m * 16 + l15;
#pragma unroll
    for (int kh = 0; kh < 2; ++kh)
      qf[m][kh] = *(const bf16x8*)(Qb + (size_t)qrow * HD + kh * 32 + g * 8);
  }

  f32x4 oacc[2][4] = {};
  float mrun[2][4], lrun[2][4];
#pragma unroll
  for (int m = 0; m < 2; ++m)
#pragma unroll
    for (int r = 0; r < 4; ++r) { mrun[m][r] = -1e30f; lrun[m][r] = 0.f; }

  const int vp = tid & 31, vcg = tid >> 5;
  const int ktend = 2 * qt + 1;

  for (int kt = 0; kt <= ktend; ++kt) {
    __syncthreads();
    // stage K tile (swizzled source -> linear LDS, read with same XOR)
#pragma unroll
    for (int j = 0; j < 2; ++j) {
      int r = j * 32 + (tid >> 3);
      const u16* gk = Kb + (size_t)(kt * 64 + r) * HD + ((tid & 7) ^ (r & 7)) * 8;
      gld_lds16(gk, (char*)Ksh + j * 4096 + wave * 1024);
    }
    // stage V transposed (reg path), swizzled: Vt[d][kv]
    {
      const u16* gv = Vb + (size_t)(kt * 64 + 2 * vp) * HD + vcg * 8;
      bf16x8 v0 = *(const bf16x8*)gv;
      bf16x8 v1 = *(const bf16x8*)(gv + HD);
#pragma unroll
      for (int j = 0; j < 8; ++j) {
        int c = vcg * 8 + j;
        int byteoff = (c * 128 + 4 * vp) ^ ((c & 7) << 4);
        unsigned int pk = (unsigned int)(u16)v0[j] | ((unsigned int)(u16)v1[j] << 16);
        *(unsigned int*)((char*)Vt + byteoff) = pk;
      }
    }
    __syncthreads();

    // S = Q K^T
    f32x4 s[2][4] = {};
#pragma unroll
    for (int kh = 0; kh < 2; ++kh) {
      bf16x8 kf[4];
#pragma unroll
      for (int n = 0; n < 4; ++n) {
        int r = n * 16 + l15;
        int ch = (kh * 4 + g) ^ (r & 7);
        kf[n] = *(const bf16x8*)((const char*)Ksh + r * 128 + ch * 16);
      }
#pragma unroll
      for (int m = 0; m < 2; ++m)
#pragma unroll
        for (int n = 0; n < 4; ++n)
          s[m][n] = __builtin_amdgcn_mfma_f32_16x16x32_bf16(qf[m][kh], kf[n], s[m][n], 0, 0, 0);
    }

    // causal mask (only needed near the diagonal)
    if (kt * 64 + 63 > qt * 128 + wave * 32) {
#pragma unroll
      for (int m = 0; m < 2; ++m)
#pragma unroll
        for (int n = 0; n < 4; ++n)
#pragma unroll
          for (int r = 0; r < 4; ++r) {
            int q = qt * 128 + wave * 32 + m * 16 + g * 4 + r;
            int kv = kt * 64 + n * 16 + l15;
            if (kv > q) s[m][n][r] = -1e30f;
          }
    }

    // online softmax (rows live across 16-lane groups; reduce with shfl_xor)
#pragma unroll
    for (int m = 0; m < 2; ++m) {
      float alpha[4];
#pragma unroll
      for (int r = 0; r < 4; ++r) {
        float rmax = fmaxf(fmaxf(s[m][0][r], s[m][1][r]), fmaxf(s[m][2][r], s[m][3][r]));
        rmax = fmaxf(rmax, __shfl_xor(rmax, 1));
        rmax = fmaxf(rmax, __shfl_xor(rmax, 2));
        rmax = fmaxf(rmax, __shfl_xor(rmax, 4));
        rmax = fmaxf(rmax, __shfl_xor(rmax, 8));
        float mnew = fmaxf(mrun[m][r], rmax);
        float a = __expf(mrun[m][r] - mnew);
        mrun[m][r] = mnew;
        float ps = 0.f;
#pragma unroll
        for (int n = 0; n < 4; ++n) {
          float p = __expf(s[m][n][r] - mnew);
          s[m][n][r] = p;
          ps += p;
        }
        ps += __shfl_xor(ps, 1);
        ps += __shfl_xor(ps, 2);
        ps += __shfl_xor(ps, 4);
        ps += __shfl_xor(ps, 8);
        lrun[m][r] = lrun[m][r] * a + ps;
        alpha[r] = a;
      }
#pragma unroll
      for (int n = 0; n < 4; ++n)
#pragma unroll
        for (int r = 0; r < 4; ++r)
          oacc[m][n][r] *= alpha[r];
      // write P (bf16) to per-wave LDS in A-operand layout (swizzled)
      char* pb = (char*)(Plds[wave]);
#pragma unroll
      for (int n = 0; n < 4; ++n)
#pragma unroll
        for (int r = 0; r < 4; ++r) {
          int qr = m * 16 + g * 4 + r;
          int off = qr * 128 + (((n * 16 + l15) * 2) ^ ((qr & 7) << 4));
          *(u16*)(pb + off) = f2bf(s[m][n][r]);
        }
    }

    // O += P @ V
#pragma unroll
    for (int kvh = 0; kvh < 2; ++kvh) {
      bf16x8 pa[2], vb2[4];
#pragma unroll
      for (int m = 0; m < 2; ++m) {
        int r = m * 16 + l15;
        int ch = (kvh * 4 + g) ^ (r & 7);
        pa[m] = *(const bf16x8*)((const char*)(Plds[wave]) + r * 128 + ch * 16);
      }
#pragma unroll
      for (int n = 0; n < 4; ++n) {
        int r = n * 16 + l15;
        int ch = (kvh * 4 + g) ^ (r & 7);
        vb2[n] = *(const bf16x8*)((const char*)Vt + r * 128 + ch * 16);
      }
#pragma unroll
      for (int m = 0; m < 2; ++m)
#pragma unroll
        for (int n = 0; n < 4; ++n)
          oacc[m][n] = __builtin_amdgcn_mfma_f32_16x16x32_bf16(pa[m], vb2[n], oacc[m][n], 0, 0, 0);
    }
  }

  // normalize + store O as bf16 [B,T,D]
  const int b = bh >> 4, h = bh & 15;
#pragma unroll
  for (int m = 0; m < 2; ++m) {
    float inv[4];
#pragma unroll
    for (int r = 0; r < 4; ++r) inv[r] = 1.f / lrun[m][r];
#pragma unroll
    for (int n = 0; n < 4; ++n)
#pragma unroll
      for (int r = 0; r < 4; ++r) {
        int t = qt * 128 + wave * 32 + m * 16 + g * 4 + r;
        int col = h * 64 + n * 16 + l15;
        Ow[((size_t)b * T + t) * DMODEL + col] = f2bf(oacc[m][n][r] * inv[r]);
      }
  }
}

extern "C" void kernel_launch(void* const* d_in, const int* in_sizes, int n_in,
                              void* d_out, int out_size, void* d_ws, size_t ws_size,
                              hipStream_t stream) {
  const float* x  = (const float*)d_in[0];
  const float* Wq = (const float*)d_in[1];
  const float* bq = (const float*)d_in[2];
  const float* Wk = (const float*)d_in[3];
  const float* bk = (const float*)d_in[4];
  const float* Wv = (const float*)d_in[5];
  const float* bv = (const float*)d_in[6];
  const float* Wo = (const float*)d_in[7];
  const float* bo = (const float*)d_in[8];
  float* out = (float*)d_out;
  u16* ws = (u16*)d_ws;

  // cast x to bf16: 8M elems, 8/thread
  k_cast<<<4096, 256, 0, stream>>>(x, ws + XB_OFF);
  // transpose+cast the 4 weights
  k_transw<<<dim3(32, 32, 4), dim3(32, 8), 0, stream>>>(Wq, Wk, Wv, Wo, ws + WT_OFF);
  // QKV projections (z = 0,1,2)
  k_gemm_qkv<<<dim3(64, 8, 3), 256, 0, stream>>>(ws + XB_OFF, ws + WT_OFF, bq, bk, bv,
                                                 ws + Q_OFF, ws + K_OFF, ws + V_OFF);
  // causal flash attention
  k_attn<<<dim3(16, 64), 256, 0, stream>>>(ws + Q_OFF, ws + K_OFF, ws + V_OFF, ws + O_OFF);
  // output projection
  k_gemm_out<<<dim3(64, 8), 256, 0, stream>>>(ws + O_OFF, ws + WT_OFF + 3ull * DMODEL * DMODEL,
                                              bo, out);
}

// Round 2
// 216.425 us; speedup vs baseline: 1.3905x; 1.3905x over previous
//
#include <hip/hip_runtime.h>
#include <cstdint>
#include <cstddef>

#define DI __device__ __forceinline__

typedef unsigned short u16;
typedef short bf16x8 __attribute__((ext_vector_type(8)));
typedef unsigned short u16x8 __attribute__((ext_vector_type(8)));
typedef float f32x4 __attribute__((ext_vector_type(4)));

static constexpr int DMODEL = 1024, T = 2048, BB = 4, NH = 16, HD = 64;
static constexpr int M = BB * T; // 8192

// workspace offsets in u16 elements
static constexpr size_t XB_OFF = 0;                                  // x bf16 [8192][1024]
static constexpr size_t WT_OFF = (size_t)M * DMODEL;                 // 4 x WtT bf16 [1024][1024]
static constexpr size_t Q_OFF  = WT_OFF + 4ull * DMODEL * DMODEL;    // Q [B,H,T,64]
static constexpr size_t K_OFF  = Q_OFF + (size_t)M * DMODEL;
static constexpr size_t V_OFF  = K_OFF + (size_t)M * DMODEL;
static constexpr size_t O_OFF  = XB_OFF;                             // attn out aliases xb

DI u16 f2bf(float x) {
  unsigned int u = __builtin_bit_cast(unsigned int, x);
  u += 0x7fffu + ((u >> 16) & 1u);
  return (u16)(u >> 16);
}

DI void gld_lds16(const void* g, void* l) {
  __builtin_amdgcn_global_load_lds(
      (const __attribute__((address_space(1))) void*)g,
      (__attribute__((address_space(3))) void*)l, 16, 0, 0);
}

// ---------------- cast x fp32 -> bf16 ----------------
__global__ void k_cast(const float* __restrict__ in, u16* __restrict__ out) {
  size_t i = (size_t)(blockIdx.x * 256 + threadIdx.x) * 8;
  float4 a = *(const float4*)(in + i);
  float4 b = *(const float4*)(in + i + 4);
  u16x8 v;
  v[0] = f2bf(a.x); v[1] = f2bf(a.y); v[2] = f2bf(a.z); v[3] = f2bf(a.w);
  v[4] = f2bf(b.x); v[5] = f2bf(b.y); v[6] = f2bf(b.z); v[7] = f2bf(b.w);
  *(u16x8*)(out + i) = v;
}

// ---------------- transpose+cast weights: W[K][N] f32 -> Wt[N][K] bf16 ----------------
__global__ void k_transw(const float* __restrict__ Wq, const float* __restrict__ Wk,
                         const float* __restrict__ Wv, const float* __restrict__ Wo,
                         u16* __restrict__ WtBase) {
  __shared__ u16 tile[32][33];
  const int z = blockIdx.z;
  const float* W = z == 0 ? Wq : (z == 1 ? Wk : (z == 2 ? Wv : Wo));
  u16* Wt = WtBase + (size_t)z * DMODEL * DMODEL;
  int tx = threadIdx.x, ty = threadIdx.y;
  int c = blockIdx.x * 32 + tx;
#pragma unroll
  for (int i = 0; i < 4; ++i) {
    int r = blockIdx.y * 32 + ty + i * 8;
    tile[ty + i * 8][tx] = f2bf(W[(size_t)r * DMODEL + c]);
  }
  __syncthreads();
#pragma unroll
  for (int i = 0; i < 4; ++i) {
    int rw = blockIdx.x * 32 + ty + i * 8;
    Wt[(size_t)rw * DMODEL + blockIdx.y * 32 + tx] = tile[tx][ty + i * 8];
  }
}

// ---------------- QKV projection GEMM: C = x @ W + b (bf16 MFMA, 128x128 tile, BK=64) ----
__launch_bounds__(256, 2)
__global__ void k_gemm_qkv(const u16* __restrict__ A, const u16* __restrict__ Wt,
                           const float* __restrict__ bq, const float* __restrict__ bk,
                           const float* __restrict__ bv,
                           u16* __restrict__ Qo, u16* __restrict__ Ko, u16* __restrict__ Vo) {
  __shared__ u16 As[128 * 64];
  __shared__ u16 Bs[128 * 64];
  const int z = blockIdx.z;
  const u16* Bt = Wt + (size_t)z * DMODEL * DMODEL;
  const float* bias = z == 0 ? bq : (z == 1 ? bk : bv);
  u16* out = z == 0 ? Qo : (z == 1 ? Ko : Vo);
  // Q gets 1/sqrt(Hd) * log2(e) folded in so softmax can use exp2
  const float scale = z == 0 ? 0.125f * 1.4426950408889634f : 1.0f;

  const int tid = threadIdx.x;
  const int wave = tid >> 6, lane = tid & 63;
  const int g = lane >> 4, l15 = lane & 15;
  const int brow = blockIdx.x * 128, bcol = blockIdx.y * 128;
  const int wr = wave >> 1, wc = wave & 1;
  const int srow = tid >> 3, schunk = tid & 7;

  f32x4 acc[4][4] = {};

  for (int k0 = 0; k0 < DMODEL; k0 += 64) {
    __syncthreads();
#pragma unroll
    for (int j = 0; j < 4; ++j) {
      int r = j * 32 + srow;
      int cs = (schunk ^ (r & 7)) * 8;
      gld_lds16(A + (size_t)(brow + r) * DMODEL + k0 + cs, (char*)As + j * 4096 + wave * 1024);
      gld_lds16(Bt + (size_t)(bcol + r) * DMODEL + k0 + cs, (char*)Bs + j * 4096 + wave * 1024);
    }
    __syncthreads();
#pragma unroll
    for (int kh = 0; kh < 2; ++kh) {
      bf16x8 af[4], bfr[4];
#pragma unroll
      for (int m = 0; m < 4; ++m) {
        int r = wr * 64 + m * 16 + l15;
        int ch = (kh * 4 + g) ^ (r & 7);
        af[m] = *(const bf16x8*)((const char*)As + r * 128 + ch * 16);
      }
#pragma unroll
      for (int n = 0; n < 4; ++n) {
        int r = wc * 64 + n * 16 + l15;
        int ch = (kh * 4 + g) ^ (r & 7);
        bfr[n] = *(const bf16x8*)((const char*)Bs + r * 128 + ch * 16);
      }
#pragma unroll
      for (int m = 0; m < 4; ++m)
#pragma unroll
        for (int n = 0; n < 4; ++n)
          acc[m][n] = __builtin_amdgcn_mfma_f32_16x16x32_bf16(af[m], bfr[n], acc[m][n], 0, 0, 0);
    }
  }

#pragma unroll
  for (int m = 0; m < 4; ++m)
#pragma unroll
    for (int n = 0; n < 4; ++n) {
      int col = bcol + wc * 64 + n * 16 + l15;
      float bias_v = bias[col];
      int h = col >> 6, d = col & 63;
#pragma unroll
      for (int r = 0; r < 4; ++r) {
        int row = brow + wr * 64 + m * 16 + g * 4 + r;
        int b = row >> 11, t = row & 2047;
        float v = (acc[m][n][r] + bias_v) * scale;
        out[(((size_t)(b * NH + h) * T + t) << 6) + d] = f2bf(v);
      }
    }
}

// ---------------- output projection GEMM: out = O @ Wo + bo (fp32 out) ----------------
__launch_bounds__(256, 2)
__global__ void k_gemm_out(const u16* __restrict__ A, const u16* __restrict__ Bt,
                           const float* __restrict__ bias, float* __restrict__ out) {
  __shared__ u16 As[128 * 64];
  __shared__ u16 Bs[128 * 64];
  const int tid = threadIdx.x;
  const int wave = tid >> 6, lane = tid & 63;
  const int g = lane >> 4, l15 = lane & 15;
  const int brow = blockIdx.x * 128, bcol = blockIdx.y * 128;
  const int wr = wave >> 1, wc = wave & 1;
  const int srow = tid >> 3, schunk = tid & 7;

  f32x4 acc[4][4] = {};

  for (int k0 = 0; k0 < DMODEL; k0 += 64) {
    __syncthreads();
#pragma unroll
    for (int j = 0; j < 4; ++j) {
      int r = j * 32 + srow;
      int cs = (schunk ^ (r & 7)) * 8;
      gld_lds16(A + (size_t)(brow + r) * DMODEL + k0 + cs, (char*)As + j * 4096 + wave * 1024);
      gld_lds16(Bt + (size_t)(bcol + r) * DMODEL + k0 + cs, (char*)Bs + j * 4096 + wave * 1024);
    }
    __syncthreads();
#pragma unroll
    for (int kh = 0; kh < 2; ++kh) {
      bf16x8 af[4], bfr[4];
#pragma unroll
      for (int m = 0; m < 4; ++m) {
        int r = wr * 64 + m * 16 + l15;
        int ch = (kh * 4 + g) ^ (r & 7);
        af[m] = *(const bf16x8*)((const char*)As + r * 128 + ch * 16);
      }
#pragma unroll
      for (int n = 0; n < 4; ++n) {
        int r = wc * 64 + n * 16 + l15;
        int ch = (kh * 4 + g) ^ (r & 7);
        bfr[n] = *(const bf16x8*)((const char*)Bs + r * 128 + ch * 16);
      }
#pragma unroll
      for (int m = 0; m < 4; ++m)
#pragma unroll
        for (int n = 0; n < 4; ++n)
          acc[m][n] = __builtin_amdgcn_mfma_f32_16x16x32_bf16(af[m], bfr[n], acc[m][n], 0, 0, 0);
    }
  }

#pragma unroll
  for (int m = 0; m < 4; ++m)
#pragma unroll
    for (int n = 0; n < 4; ++n) {
      int col = bcol + wc * 64 + n * 16 + l15;
      float bias_v = bias[col];
#pragma unroll
      for (int r = 0; r < 4; ++r) {
        int row = brow + wr * 64 + m * 16 + g * 4 + r;
        out[(size_t)row * DMODEL + col] = acc[m][n][r] + bias_v;
      }
    }
}

// ---------------- causal flash attention ----------------
// grid (16, 64): x = q-tile PAIR index (uniform cost), y = b*16+h
// block 256 = 4 waves x 16 q-rows = 64 q-rows per tile; KV tiles of 64.
// Each block processes q-tiles {31-qp, qp} -> exactly 33 KV tiles each.
__launch_bounds__(256, 4)
__global__ void k_attn(const u16* __restrict__ Qw, const u16* __restrict__ Kw,
                       const u16* __restrict__ Vw, u16* __restrict__ Ow) {
  __shared__ u16 Ksh[64 * 64];
  __shared__ u16 Vt[64 * 64];
  __shared__ u16 Plds[4][16 * 64];

  const int tid = threadIdx.x;
  const int wave = tid >> 6, lane = tid & 63;
  const int g = lane >> 4, l15 = lane & 15;
  const int qp = blockIdx.x;
  const int bh = blockIdx.y;
  const u16* Qb = Qw + (size_t)bh * T * HD;
  const u16* Kb = Kw + (size_t)bh * T * HD;
  const u16* Vb = Vw + (size_t)bh * T * HD;
  const int b = bh >> 4, h = bh & 15;
  const int vp = tid & 31, vcg = tid >> 5;

#pragma unroll
  for (int half = 0; half < 2; ++half) {
    const int qt = half == 0 ? (31 - qp) : qp;
    const int ntiles = qt + 1;

    // Q fragments in registers (Q pre-scaled by 1/8*log2e)
    bf16x8 qf[2];
    {
      int qrow = qt * 64 + wave * 16 + l15;
#pragma unroll
      for (int kh = 0; kh < 2; ++kh)
        qf[kh] = *(const bf16x8*)(Qb + (size_t)qrow * HD + kh * 32 + g * 8);
    }

    f32x4 oacc[4] = {};
    float mrun[4], lrun[4];
#pragma unroll
    for (int r = 0; r < 4; ++r) { mrun[r] = -1e30f; lrun[r] = 0.f; }

    for (int kt = 0; kt < ntiles; ++kt) {
      __syncthreads();
      // stage K tile (swizzled source -> linear LDS, read with same XOR)
#pragma unroll
      for (int j = 0; j < 2; ++j) {
        int r = j * 32 + (tid >> 3);
        const u16* gk = Kb + (size_t)(kt * 64 + r) * HD + ((tid & 7) ^ (r & 7)) * 8;
        gld_lds16(gk, (char*)Ksh + j * 4096 + wave * 1024);
      }
      // stage V transposed (reg path), swizzled: Vt[d][kv]
      {
        const u16* gv = Vb + (size_t)(kt * 64 + 2 * vp) * HD + vcg * 8;
        bf16x8 v0 = *(const bf16x8*)gv;
        bf16x8 v1 = *(const bf16x8*)(gv + HD);
#pragma unroll
        for (int j = 0; j < 8; ++j) {
          int c = vcg * 8 + j;
          int byteoff = (c * 128 + 4 * vp) ^ ((c & 7) << 4);
          unsigned int pk = (unsigned int)(u16)v0[j] | ((unsigned int)(u16)v1[j] << 16);
          *(unsigned int*)((char*)Vt + byteoff) = pk;
        }
      }
      __syncthreads();

      // S = Q K^T  (16 q-rows x 64 kv)
      f32x4 s[4] = {};
#pragma unroll
      for (int kh = 0; kh < 2; ++kh) {
        bf16x8 kf[4];
#pragma unroll
        for (int n = 0; n < 4; ++n) {
          int r = n * 16 + l15;
          int ch = (kh * 4 + g) ^ (r & 7);
          kf[n] = *(const bf16x8*)((const char*)Ksh + r * 128 + ch * 16);
        }
#pragma unroll
        for (int n = 0; n < 4; ++n)
          s[n] = __builtin_amdgcn_mfma_f32_16x16x32_bf16(qf[kh], kf[n], s[n], 0, 0, 0);
      }

      // causal mask (only the diagonal tile needs it)
      if (kt == qt) {
#pragma unroll
        for (int n = 0; n < 4; ++n)
#pragma unroll
          for (int r = 0; r < 4; ++r) {
            int q = qt * 64 + wave * 16 + g * 4 + r;
            int kv = kt * 64 + n * 16 + l15;
            if (kv > q) s[n][r] = -1e30f;
          }
      }

      // online softmax (base-2; rows live across 16-lane groups)
      float alpha[4];
#pragma unroll
      for (int r = 0; r < 4; ++r) {
        float rmax = fmaxf(fmaxf(s[0][r], s[1][r]), fmaxf(s[2][r], s[3][r]));
        rmax = fmaxf(rmax, __shfl_xor(rmax, 1));
        rmax = fmaxf(rmax, __shfl_xor(rmax, 2));
        rmax = fmaxf(rmax, __shfl_xor(rmax, 4));
        rmax = fmaxf(rmax, __shfl_xor(rmax, 8));
        float mnew = fmaxf(mrun[r], rmax);
        float a = exp2f(mrun[r] - mnew);
        mrun[r] = mnew;
        float ps = 0.f;
#pragma unroll
        for (int n = 0; n < 4; ++n) {
          float p = exp2f(s[n][r] - mnew);
          s[n][r] = p;
          ps += p;
        }
        ps += __shfl_xor(ps, 1);
        ps += __shfl_xor(ps, 2);
        ps += __shfl_xor(ps, 4);
        ps += __shfl_xor(ps, 8);
        lrun[r] = lrun[r] * a + ps;
        alpha[r] = a;
      }
#pragma unroll
      for (int n = 0; n < 4; ++n)
#pragma unroll
        for (int r = 0; r < 4; ++r)
          oacc[n][r] *= alpha[r];
      // write P (bf16) to per-wave LDS in A-operand layout (swizzled)
      {
        char* pb = (char*)(Plds[wave]);
#pragma unroll
        for (int n = 0; n < 4; ++n)
#pragma unroll
          for (int r = 0; r < 4; ++r) {
            int qr = g * 4 + r;
            int off = qr * 128 + (((n * 16 + l15) * 2) ^ ((qr & 7) << 4));
            *(u16*)(pb + off) = f2bf(s[n][r]);
          }
      }

      // O += P @ V
#pragma unroll
      for (int kvh = 0; kvh < 2; ++kvh) {
        bf16x8 pa, vb2[4];
        {
          int r = l15;
          int ch = (kvh * 4 + g) ^ (r & 7);
          pa = *(const bf16x8*)((const char*)(Plds[wave]) + r * 128 + ch * 16);
        }
#pragma unroll
        for (int n = 0; n < 4; ++n) {
          int r = n * 16 + l15;
          int ch = (kvh * 4 + g) ^ (r & 7);
          vb2[n] = *(const bf16x8*)((const char*)Vt + r * 128 + ch * 16);
        }
#pragma unroll
        for (int n = 0; n < 4; ++n)
          oacc[n] = __builtin_amdgcn_mfma_f32_16x16x32_bf16(pa, vb2[n], oacc[n], 0, 0, 0);
      }
    }

    // normalize + store O as bf16 [B,T,D]
    float inv[4];
#pragma unroll
    for (int r = 0; r < 4; ++r) inv[r] = 1.f / lrun[r];
#pragma unroll
    for (int n = 0; n < 4; ++n)
#pragma unroll
      for (int r = 0; r < 4; ++r) {
        int t = qt * 64 + wave * 16 + g * 4 + r;
        int col = h * 64 + n * 16 + l15;
        Ow[((size_t)b * T + t) * DMODEL + col] = f2bf(oacc[n][r] * inv[r]);
      }
  }
}

extern "C" void kernel_launch(void* const* d_in, const int* in_sizes, int n_in,
                              void* d_out, int out_size, void* d_ws, size_t ws_size,
                              hipStream_t stream) {
  const float* x  = (const float*)d_in[0];
  const float* Wq = (const float*)d_in[1];
  const float* bq = (const float*)d_in[2];
  const float* Wk = (const float*)d_in[3];
  const float* bk = (const float*)d_in[4];
  const float* Wv = (const float*)d_in[5];
  const float* bv = (const float*)d_in[6];
  const float* Wo = (const float*)d_in[7];
  const float* bo = (const float*)d_in[8];
  float* out = (float*)d_out;
  u16* ws = (u16*)d_ws;

  // cast x to bf16: 8M elems, 8/thread
  k_cast<<<4096, 256, 0, stream>>>(x, ws + XB_OFF);
  // transpose+cast the 4 weights
  k_transw<<<dim3(32, 32, 4), dim3(32, 8), 0, stream>>>(Wq, Wk, Wv, Wo, ws + WT_OFF);
  // QKV projections (z = 0,1,2)
  k_gemm_qkv<<<dim3(64, 8, 3), 256, 0, stream>>>(ws + XB_OFF, ws + WT_OFF, bq, bk, bv,
                                                 ws + Q_OFF, ws + K_OFF, ws + V_OFF);
  // causal flash attention (paired q-tiles, uniform cost)
  k_attn<<<dim3(16, 64), 256, 0, stream>>>(ws + Q_OFF, ws + K_OFF, ws + V_OFF, ws + O_OFF);
  // output projection
  k_gemm_out<<<dim3(64, 8), 256, 0, stream>>>(ws + O_OFF, ws + WT_OFF + 3ull * DMODEL * DMODEL,
                                              bo, out);
}

// Round 3
// 182.857 us; speedup vs baseline: 1.6458x; 1.1836x over previous
//
#include <hip/hip_runtime.h>
#include <cstdint>
#include <cstddef>

#define DI __device__ __forceinline__

typedef unsigned short u16;
typedef short bf16x8 __attribute__((ext_vector_type(8)));
typedef unsigned short u16x8 __attribute__((ext_vector_type(8)));
typedef float f32x4 __attribute__((ext_vector_type(4)));

static constexpr int DMODEL = 1024, T = 2048, BB = 4, NH = 16, HD = 64;
static constexpr int M = BB * T; // 8192

// workspace offsets in u16 elements
static constexpr size_t XB_OFF = 0;                                  // x bf16 [8192][1024]
static constexpr size_t WT_OFF = (size_t)M * DMODEL;                 // 4 x WtT bf16 [1024][1024]
static constexpr size_t Q_OFF  = WT_OFF + 4ull * DMODEL * DMODEL;    // Q [B,H,T,64]
static constexpr size_t K_OFF  = Q_OFF + (size_t)M * DMODEL;
static constexpr size_t V_OFF  = K_OFF + (size_t)M * DMODEL;
static constexpr size_t O_OFF  = XB_OFF;                             // attn out aliases xb

DI u16 f2bf(float x) {
  unsigned int u = __builtin_bit_cast(unsigned int, x);
  u += 0x7fffu + ((u >> 16) & 1u);
  return (u16)(u >> 16);
}

DI unsigned int cvtpk_bf16(float a, float b) {
  unsigned int r;
  asm("v_cvt_pk_bf16_f32 %0, %1, %2" : "=v"(r) : "v"(a), "v"(b));
  return r;
}

DI void gld_lds16(const void* g, void* l) {
  __builtin_amdgcn_global_load_lds(
      (const __attribute__((address_space(1))) void*)g,
      (__attribute__((address_space(3))) void*)l, 16, 0, 0);
}

// ---------------- cast x fp32 -> bf16 ----------------
__global__ void k_cast(const float* __restrict__ in, u16* __restrict__ out) {
  size_t i = (size_t)(blockIdx.x * 256 + threadIdx.x) * 8;
  float4 a = *(const float4*)(in + i);
  float4 b = *(const float4*)(in + i + 4);
  u16x8 v;
  v[0] = f2bf(a.x); v[1] = f2bf(a.y); v[2] = f2bf(a.z); v[3] = f2bf(a.w);
  v[4] = f2bf(b.x); v[5] = f2bf(b.y); v[6] = f2bf(b.z); v[7] = f2bf(b.w);
  *(u16x8*)(out + i) = v;
}

// ---------------- transpose+cast weights: W[K][N] f32 -> Wt[N][K] bf16 ----------------
__global__ void k_transw(const float* __restrict__ Wq, const float* __restrict__ Wk,
                         const float* __restrict__ Wv, const float* __restrict__ Wo,
                         u16* __restrict__ WtBase) {
  __shared__ u16 tile[32][33];
  const int z = blockIdx.z;
  const float* W = z == 0 ? Wq : (z == 1 ? Wk : (z == 2 ? Wv : Wo));
  u16* Wt = WtBase + (size_t)z * DMODEL * DMODEL;
  int tx = threadIdx.x, ty = threadIdx.y;
  int c = blockIdx.x * 32 + tx;
#pragma unroll
  for (int i = 0; i < 4; ++i) {
    int r = blockIdx.y * 32 + ty + i * 8;
    tile[ty + i * 8][tx] = f2bf(W[(size_t)r * DMODEL + c]);
  }
  __syncthreads();
#pragma unroll
  for (int i = 0; i < 4; ++i) {
    int rw = blockIdx.x * 32 + ty + i * 8;
    Wt[(size_t)rw * DMODEL + blockIdx.y * 32 + tx] = tile[tx][ty + i * 8];
  }
}

// ---------------- QKV projection GEMM: C = x @ W + b (bf16 MFMA, 128x128 tile, BK=64) ----
__launch_bounds__(256, 2)
__global__ void k_gemm_qkv(const u16* __restrict__ A, const u16* __restrict__ Wt,
                           const float* __restrict__ bq, const float* __restrict__ bk,
                           const float* __restrict__ bv,
                           u16* __restrict__ Qo, u16* __restrict__ Ko, u16* __restrict__ Vo) {
  __shared__ u16 As[128 * 64];
  __shared__ u16 Bs[128 * 64];
  const int z = blockIdx.z;
  const u16* Bt = Wt + (size_t)z * DMODEL * DMODEL;
  const float* bias = z == 0 ? bq : (z == 1 ? bk : bv);
  u16* out = z == 0 ? Qo : (z == 1 ? Ko : Vo);
  // Q gets 1/sqrt(Hd) * log2(e) folded in so softmax can use exp2
  const float scale = z == 0 ? 0.125f * 1.4426950408889634f : 1.0f;

  const int tid = threadIdx.x;
  const int wave = tid >> 6, lane = tid & 63;
  const int g = lane >> 4, l15 = lane & 15;
  const int brow = blockIdx.x * 128, bcol = blockIdx.y * 128;
  const int wr = wave >> 1, wc = wave & 1;
  const int srow = tid >> 3, schunk = tid & 7;

  f32x4 acc[4][4] = {};

  for (int k0 = 0; k0 < DMODEL; k0 += 64) {
    __syncthreads();
#pragma unroll
    for (int j = 0; j < 4; ++j) {
      int r = j * 32 + srow;
      int cs = (schunk ^ (r & 7)) * 8;
      gld_lds16(A + (size_t)(brow + r) * DMODEL + k0 + cs, (char*)As + j * 4096 + wave * 1024);
      gld_lds16(Bt + (size_t)(bcol + r) * DMODEL + k0 + cs, (char*)Bs + j * 4096 + wave * 1024);
    }
    __syncthreads();
#pragma unroll
    for (int kh = 0; kh < 2; ++kh) {
      bf16x8 af[4], bfr[4];
#pragma unroll
      for (int m = 0; m < 4; ++m) {
        int r = wr * 64 + m * 16 + l15;
        int ch = (kh * 4 + g) ^ (r & 7);
        af[m] = *(const bf16x8*)((const char*)As + r * 128 + ch * 16);
      }
#pragma unroll
      for (int n = 0; n < 4; ++n) {
        int r = wc * 64 + n * 16 + l15;
        int ch = (kh * 4 + g) ^ (r & 7);
        bfr[n] = *(const bf16x8*)((const char*)Bs + r * 128 + ch * 16);
      }
#pragma unroll
      for (int m = 0; m < 4; ++m)
#pragma unroll
        for (int n = 0; n < 4; ++n)
          acc[m][n] = __builtin_amdgcn_mfma_f32_16x16x32_bf16(af[m], bfr[n], acc[m][n], 0, 0, 0);
    }
  }

#pragma unroll
  for (int m = 0; m < 4; ++m)
#pragma unroll
    for (int n = 0; n < 4; ++n) {
      int col = bcol + wc * 64 + n * 16 + l15;
      float bias_v = bias[col];
      int h = col >> 6, d = col & 63;
#pragma unroll
      for (int r = 0; r < 4; ++r) {
        int row = brow + wr * 64 + m * 16 + g * 4 + r;
        int b = row >> 11, t = row & 2047;
        float v = (acc[m][n][r] + bias_v) * scale;
        out[(((size_t)(b * NH + h) * T + t) << 6) + d] = f2bf(v);
      }
    }
}

// ---------------- output projection GEMM: out = O @ Wo + bo (fp32 out) ----------------
__launch_bounds__(256, 2)
__global__ void k_gemm_out(const u16* __restrict__ A, const u16* __restrict__ Bt,
                           const float* __restrict__ bias, float* __restrict__ out) {
  __shared__ u16 As[128 * 64];
  __shared__ u16 Bs[128 * 64];
  const int tid = threadIdx.x;
  const int wave = tid >> 6, lane = tid & 63;
  const int g = lane >> 4, l15 = lane & 15;
  const int brow = blockIdx.x * 128, bcol = blockIdx.y * 128;
  const int wr = wave >> 1, wc = wave & 1;
  const int srow = tid >> 3, schunk = tid & 7;

  f32x4 acc[4][4] = {};

  for (int k0 = 0; k0 < DMODEL; k0 += 64) {
    __syncthreads();
#pragma unroll
    for (int j = 0; j < 4; ++j) {
      int r = j * 32 + srow;
      int cs = (schunk ^ (r & 7)) * 8;
      gld_lds16(A + (size_t)(brow + r) * DMODEL + k0 + cs, (char*)As + j * 4096 + wave * 1024);
      gld_lds16(Bt + (size_t)(bcol + r) * DMODEL + k0 + cs, (char*)Bs + j * 4096 + wave * 1024);
    }
    __syncthreads();
#pragma unroll
    for (int kh = 0; kh < 2; ++kh) {
      bf16x8 af[4], bfr[4];
#pragma unroll
      for (int m = 0; m < 4; ++m) {
        int r = wr * 64 + m * 16 + l15;
        int ch = (kh * 4 + g) ^ (r & 7);
        af[m] = *(const bf16x8*)((const char*)As + r * 128 + ch * 16);
      }
#pragma unroll
      for (int n = 0; n < 4; ++n) {
        int r = wc * 64 + n * 16 + l15;
        int ch = (kh * 4 + g) ^ (r & 7);
        bfr[n] = *(const bf16x8*)((const char*)Bs + r * 128 + ch * 16);
      }
#pragma unroll
      for (int m = 0; m < 4; ++m)
#pragma unroll
        for (int n = 0; n < 4; ++n)
          acc[m][n] = __builtin_amdgcn_mfma_f32_16x16x32_bf16(af[m], bfr[n], acc[m][n], 0, 0, 0);
    }
  }

#pragma unroll
  for (int m = 0; m < 4; ++m)
#pragma unroll
    for (int n = 0; n < 4; ++n) {
      int col = bcol + wc * 64 + n * 16 + l15;
      float bias_v = bias[col];
#pragma unroll
      for (int r = 0; r < 4; ++r) {
        int row = brow + wr * 64 + m * 16 + g * 4 + r;
        out[(size_t)row * DMODEL + col] = acc[m][n][r] + bias_v;
      }
    }
}

// ---------------- causal flash attention (swapped QK^T, lane-local softmax) -------------
// grid (16, 64): x = q-tile PAIR index (uniform cost), y = b*16+h
// block 256 = 4 waves x 16 q-rows = 64 q-rows per tile; KV tiles of 64.
// Each block processes q-tiles {31-qp, qp} -> exactly 33 KV tiles each.
// S^T = mfma(K,Q): lane (g,l15) holds S^T[kv=n*16+g*4+r][q=l15] -> row softmax is
// 15 local fmax + shfl_xor(16,32); P packed via v_cvt_pk_bf16_f32 into per-wave
// swizzled LDS (A-operand layout), read back for PV.
__launch_bounds__(256, 4)
__global__ void k_attn(const u16* __restrict__ Qw, const u16* __restrict__ Kw,
                       const u16* __restrict__ Vw, u16* __restrict__ Ow) {
  __shared__ u16 Ksh[64 * 64];
  __shared__ u16 Vt[64 * 64];
  __shared__ u16 Plds[4][16 * 64];

  const int tid = threadIdx.x;
  const int wave = tid >> 6, lane = tid & 63;
  const int g = lane >> 4, l15 = lane & 15;
  const int qp = blockIdx.x;
  const int bh = blockIdx.y;
  const u16* Qb = Qw + (size_t)bh * T * HD;
  const u16* Kb = Kw + (size_t)bh * T * HD;
  const u16* Vb = Vw + (size_t)bh * T * HD;
  const int b = bh >> 4, h = bh & 15;
  const int vp = tid & 31, vcg = tid >> 5;
  // src lane (same g-group) holding row-state for q-row g*4+r: base + r
  const int bcast_base = (lane & 48) + ((lane & 48) >> 2);

#pragma unroll
  for (int half = 0; half < 2; ++half) {
    const int qt = half == 0 ? (31 - qp) : qp;
    const int ntiles = qt + 1;

    // Q fragments in registers (Q pre-scaled by 1/8*log2e)
    bf16x8 qf[2];
    {
      int qrow = qt * 64 + wave * 16 + l15;
#pragma unroll
      for (int kh = 0; kh < 2; ++kh)
        qf[kh] = *(const bf16x8*)(Qb + (size_t)qrow * HD + kh * 32 + g * 8);
    }

    f32x4 oacc[4] = {};
    float mrun = -1e30f, lrun = 0.f;  // per-lane state for q-row = l15 (replicated over g)

    for (int kt = 0; kt < ntiles; ++kt) {
      __syncthreads();
      // stage K tile (swizzled source -> linear LDS, read with same XOR)
#pragma unroll
      for (int j = 0; j < 2; ++j) {
        int r = j * 32 + (tid >> 3);
        const u16* gk = Kb + (size_t)(kt * 64 + r) * HD + ((tid & 7) ^ (r & 7)) * 8;
        gld_lds16(gk, (char*)Ksh + j * 4096 + wave * 1024);
      }
      // stage V transposed (reg path), swizzled: Vt[d][kv]
      {
        const u16* gv = Vb + (size_t)(kt * 64 + 2 * vp) * HD + vcg * 8;
        bf16x8 v0 = *(const bf16x8*)gv;
        bf16x8 v1 = *(const bf16x8*)(gv + HD);
#pragma unroll
        for (int j = 0; j < 8; ++j) {
          int c = vcg * 8 + j;
          int byteoff = (c * 128 + 4 * vp) ^ ((c & 7) << 4);
          unsigned int pk = (unsigned int)(u16)v0[j] | ((unsigned int)(u16)v1[j] << 16);
          *(unsigned int*)((char*)Vt + byteoff) = pk;
        }
      }
      __syncthreads();

      // S^T = K Q^T : lane (g,l15) holds S^T[kv=n*16+g*4+r][q=l15]
      f32x4 s[4] = {};
#pragma unroll
      for (int kh = 0; kh < 2; ++kh) {
        bf16x8 kf[4];
#pragma unroll
        for (int n = 0; n < 4; ++n) {
          int r = n * 16 + l15;
          int ch = (kh * 4 + g) ^ (r & 7);
          kf[n] = *(const bf16x8*)((const char*)Ksh + r * 128 + ch * 16);
        }
#pragma unroll
        for (int n = 0; n < 4; ++n)
          s[n] = __builtin_amdgcn_mfma_f32_16x16x32_bf16(kf[n], qf[kh], s[n], 0, 0, 0);
      }

      // causal mask (only the diagonal tile needs it)
      if (kt == qt) {
        int q_in = wave * 16 + l15;  // q within the 64-row band... (q global - qt*64)
#pragma unroll
        for (int n = 0; n < 4; ++n)
#pragma unroll
          for (int r = 0; r < 4; ++r) {
            int kv_in = n * 16 + g * 4 + r;  // kv within tile (kt==qt band)
            // global: q = qt*64 + wave*16 + l15 ; kv = kt*64 + kv_in
            if (kv_in > (half == 0 ? q_in : q_in) || (kv_in > q_in)) {}
            if (kv_in > q_in) s[n][r] = -1e30f;
          }
      }

      // wait: q band is 64 rows but each wave owns rows wave*16..wave*16+15 -> q_in above
      // is correct only when comparing within the same 64-row tile; kv_in ranges 0..63.

      // lane-local softmax over the full kv-row (16 local + cross-g)
      float vmax = s[0][0];
#pragma unroll
      for (int n = 0; n < 4; ++n)
#pragma unroll
        for (int r = 0; r < 4; ++r) vmax = fmaxf(vmax, s[n][r]);
      vmax = fmaxf(vmax, __shfl_xor(vmax, 16));
      vmax = fmaxf(vmax, __shfl_xor(vmax, 32));
      float mnew = fmaxf(mrun, vmax);
      float a = exp2f(mrun - mnew);
      mrun = mnew;
      float ps = 0.f;
#pragma unroll
      for (int n = 0; n < 4; ++n)
#pragma unroll
        for (int r = 0; r < 4; ++r) {
          float p = exp2f(s[n][r] - mnew);
          s[n][r] = p;
          ps += p;
        }
      ps += __shfl_xor(ps, 16);
      ps += __shfl_xor(ps, 32);
      lrun = lrun * a + ps;

      // broadcast alpha to O-layout rows (q = g*4+r lives at lane bcast_base+r)
      float alpha4[4];
#pragma unroll
      for (int r = 0; r < 4; ++r) alpha4[r] = __shfl(a, bcast_base + r);
#pragma unroll
      for (int n = 0; n < 4; ++n)
#pragma unroll
        for (int r = 0; r < 4; ++r) oacc[n][r] *= alpha4[r];

      // pack P pairs (kv = n*16+g*4+2i, +1) and store to per-wave swizzled LDS
      {
        char* pb = (char*)(Plds[wave]);
#pragma unroll
        for (int n = 0; n < 4; ++n)
#pragma unroll
          for (int i = 0; i < 2; ++i) {
            unsigned int w = cvtpk_bf16(s[n][2 * i], s[n][2 * i + 1]);
            int p = n * 8 + g * 2 + i;  // kv-pair index
            int off = l15 * 128 + (((p >> 2) ^ (l15 & 7)) << 4) + (p & 3) * 4;
            *(unsigned int*)(pb + off) = w;
          }
      }

      // O += P @ V
#pragma unroll
      for (int kvh = 0; kvh < 2; ++kvh) {
        bf16x8 pa, vb2[4];
        {
          int r = l15;
          int ch = (kvh * 4 + g) ^ (r & 7);
          pa = *(const bf16x8*)((const char*)(Plds[wave]) + r * 128 + ch * 16);
        }
#pragma unroll
        for (int n = 0; n < 4; ++n) {
          int r = n * 16 + l15;
          int ch = (kvh * 4 + g) ^ (r & 7);
          vb2[n] = *(const bf16x8*)((const char*)Vt + r * 128 + ch * 16);
        }
#pragma unroll
        for (int n = 0; n < 4; ++n)
          oacc[n] = __builtin_amdgcn_mfma_f32_16x16x32_bf16(pa, vb2[n], oacc[n], 0, 0, 0);
      }
    }

    // normalize + store O as bf16 [B,T,D]
    float inv = 1.f / lrun;  // for q-row l15
    float inv4[4];
#pragma unroll
    for (int r = 0; r < 4; ++r) inv4[r] = __shfl(inv, bcast_base + r);
#pragma unroll
    for (int n = 0; n < 4; ++n)
#pragma unroll
      for (int r = 0; r < 4; ++r) {
        int t = qt * 64 + wave * 16 + g * 4 + r;
        int col = h * 64 + n * 16 + l15;
        Ow[((size_t)b * T + t) * DMODEL + col] = f2bf(oacc[n][r] * inv4[r]);
      }
  }
}

extern "C" void kernel_launch(void* const* d_in, const int* in_sizes, int n_in,
                              void* d_out, int out_size, void* d_ws, size_t ws_size,
                              hipStream_t stream) {
  const float* x  = (const float*)d_in[0];
  const float* Wq = (const float*)d_in[1];
  const float* bq = (const float*)d_in[2];
  const float* Wk = (const float*)d_in[3];
  const float* bk = (const float*)d_in[4];
  const float* Wv = (const float*)d_in[5];
  const float* bv = (const float*)d_in[6];
  const float* Wo = (const float*)d_in[7];
  const float* bo = (const float*)d_in[8];
  float* out = (float*)d_out;
  u16* ws = (u16*)d_ws;

  // cast x to bf16: 8M elems, 8/thread
  k_cast<<<4096, 256, 0, stream>>>(x, ws + XB_OFF);
  // transpose+cast the 4 weights
  k_transw<<<dim3(32, 32, 4), dim3(32, 8), 0, stream>>>(Wq, Wk, Wv, Wo, ws + WT_OFF);
  // QKV projections (z = 0,1,2)
  k_gemm_qkv<<<dim3(64, 8, 3), 256, 0, stream>>>(ws + XB_OFF, ws + WT_OFF, bq, bk, bv,
                                                 ws + Q_OFF, ws + K_OFF, ws + V_OFF);
  // causal flash attention (paired q-tiles, swapped QK^T)
  k_attn<<<dim3(16, 64), 256, 0, stream>>>(ws + Q_OFF, ws + K_OFF, ws + V_OFF, ws + O_OFF);
  // output projection
  k_gemm_out<<<dim3(64, 8), 256, 0, stream>>>(ws + O_OFF, ws + WT_OFF + 3ull * DMODEL * DMODEL,
                                              bo, out);
}